// Round 1
// 878.909 us; speedup vs baseline: 2.6316x; 2.6316x over previous
//
#include <hip/hip_runtime.h>
#include <utility>

#define NM 16
#define NS 16384
#define DIMV 512

// Compile-time loop: fold expression guarantees full expansion at the AST
// level -- there is no runtime loop the compiler can decline to unroll.
// Every v[][] index below is a compile-time constant, so SROA promotes the
// whole array into VGPRs (previous version spilled: VGPR_Count=56, 7x HBM
// over-traffic from scratch).
template <typename F, int... Is>
__device__ __forceinline__ void sf_impl(F&& f, std::integer_sequence<int, Is...>) {
    (f(std::integral_constant<int, Is>{}), ...);
}
template <int N, typename F>
__device__ __forceinline__ void static_for(F&& f) {
    sf_impl(static_cast<F&&>(f), std::make_integer_sequence<int, N>{});
}

// One 64-lane wave per sample. Each lane holds 8 elements (2x float4) of each
// of the 16 vectors -> v[16][8] fully register-resident. Classical
// Gram-Schmidt (matches the reference's einsum-all-then-subtract order).
// Wave-wide shfl_xor butterfly reductions, batched per outer step i so the i
// independent dot reductions pipeline.
// __launch_bounds__(256, 2): 2 waves/EU min -> 256-VGPR budget, est. need ~180.
__global__ __launch_bounds__(256, 2) void ortho_gs_kernel(const float* __restrict__ x,
                                                          float* __restrict__ out) {
    const int gtid = blockIdx.x * blockDim.x + threadIdx.x;
    const int s    = gtid >> 6;          // sample = global wave id
    const int lane = threadIdx.x & 63;
    if (s >= NS) return;

    float v[NM][8];

    // Load: for vector m, lanes read a contiguous 1KB chunk (float4 per lane),
    // twice (elements d = lane*4..lane*4+3 and 256+lane*4..+3).
    static_for<NM>([&](auto M) {
        constexpr int m = M.value;
        const float4* p = (const float4*)(x + (size_t)m * (size_t)NS * DIMV
                                            + (size_t)s * DIMV);
        float4 a = p[lane];
        float4 b = p[64 + lane];
        v[m][0] = a.x; v[m][1] = a.y; v[m][2] = a.z; v[m][3] = a.w;
        v[m][4] = b.x; v[m][5] = b.y; v[m][6] = b.z; v[m][7] = b.w;
    });

    // Classical Gram-Schmidt, fully expanded (compile-time register indexing).
    static_for<NM>([&](auto I) {
        constexpr int i = I.value;
        float c[NM > 1 ? NM : 1];
        // Partial dot products of v[i] against all previous basis vectors.
        static_for<NM>([&](auto J) {
            constexpr int j = J.value;
            if constexpr (j < i) {
                float p = 0.f;
                static_for<8>([&](auto E) {
                    constexpr int e = E.value;
                    p = fmaf(v[i][e], v[j][e], p);
                });
                c[j] = p;
            }
        });
        // Batched butterfly reduction across the wave (independent per j, so
        // the i reductions pipeline within each round).
        static_for<6>([&](auto ST) {
            constexpr int st = 1 << ST.value;
            static_for<NM>([&](auto J) {
                constexpr int j = J.value;
                if constexpr (j < i) c[j] += __shfl_xor(c[j], st, 64);
            });
        });
        // Subtract all projections (classical GS, like the reference).
        static_for<NM>([&](auto J) {
            constexpr int j = J.value;
            if constexpr (j < i) {
                static_for<8>([&](auto E) {
                    constexpr int e = E.value;
                    v[i][e] = fmaf(-c[j], v[j][e], v[i][e]);
                });
            }
        });
        // Normalize.
        float n = 0.f;
        static_for<8>([&](auto E) {
            constexpr int e = E.value;
            n = fmaf(v[i][e], v[i][e], n);
        });
        static_for<6>([&](auto ST) {
            constexpr int st = 1 << ST.value;
            n += __shfl_xor(n, st, 64);
        });
        const float inv = 1.0f / sqrtf(n);
        static_for<8>([&](auto E) {
            constexpr int e = E.value;
            v[i][e] *= inv;
        });
    });

    // Store in the same layout: out[k, s, d].
    static_for<NM>([&](auto M) {
        constexpr int m = M.value;
        float4* p = (float4*)(out + (size_t)m * (size_t)NS * DIMV
                                  + (size_t)s * DIMV);
        p[lane]      = make_float4(v[m][0], v[m][1], v[m][2], v[m][3]);
        p[64 + lane] = make_float4(v[m][4], v[m][5], v[m][6], v[m][7]);
    });
}

extern "C" void kernel_launch(void* const* d_in, const int* in_sizes, int n_in,
                              void* d_out, int out_size, void* d_ws, size_t ws_size,
                              hipStream_t stream) {
    const float* x = (const float*)d_in[0];
    float* out = (float*)d_out;
    // One wave per sample: 16384 waves; 4 waves per 256-thread block.
    const int threads = 256;
    const int waves_per_block = threads / 64;
    const int blocks = (NS + waves_per_block - 1) / waves_per_block;
    ortho_gs_kernel<<<blocks, threads, 0, stream>>>(x, out);
}